// Round 6
// baseline (483.556 us; speedup 1.0000x reference)
//
#include <hip/hip_runtime.h>
#include <math.h>

typedef float f32x4 __attribute__((ext_vector_type(4)));
typedef __bf16 bf16x8 __attribute__((ext_vector_type(8)));
typedef unsigned short u16x8 __attribute__((ext_vector_type(8)));

__device__ __forceinline__ unsigned short f2bf(float f) {
    __bf16 h = (__bf16)f;                 // native v_cvt (RNE), pairs fuse to
    unsigned short u;                     // v_cvt_pk_bf16_f32
    __builtin_memcpy(&u, &h, 2);
    return u;
}
__device__ __forceinline__ float bf_lo(unsigned int d) {
    union { unsigned int u; float f; } v; v.u = d << 16; return v.f;
}
__device__ __forceinline__ float bf_hi(unsigned int d) {
    union { unsigned int u; float f; } v; v.u = d & 0xffff0000u; return v.f;
}
__device__ __forceinline__ float sigmoidf_(float v) {
    return 1.f / (1.f + __expf(-v));
}

// ---------------------------------------------------------------------------
// Single fused kernel, PLAIN launch (graph-capturable), hand-rolled
// device-scope grid barrier between phase 1 (GEMMs + x->bf16) and phase 2
// (score/softmax/matvec).
//
// Co-residency by construction (required for the spin barrier): 512 blocks x
// 1024 thr, LDS 72KB (2 blocks/CU of 160KB), VGPR<=64 via
// __launch_bounds__(1024,8) -> exactly 2 blocks/CU, all 512 resident.
//
// Barrier: writer side __threadfence() + release-RMW atomicAdd(bar) at agent
// scope; one thread per block spins on an ACQUIRE agent-scope load (emits
// cache invalidate -> cross-XCD visibility per G16), then __syncthreads.
// bar is hipMemsetAsync'd to 0 each launch (stream-ordered), so the
// harness's workspace re-poison cannot corrupt it.
//
// Phase 1 jobs, vb = sub*512 + blockIdx (every block gets one GEMM job):
//   vb <  512 : GEMM (b = vb>>6, tile t = vb&63; t<32 left, else right)
//   vb <  768 : conv xbf = bf16(x)
//   else      : idle (barrier skeleton only)
// left  -> LpT[b][i>>2][e][i&3] = C + b_lin[e]  (fp32, i-tile-blocked T)
// right -> R2[b][(e>>3)*2048 + j*8 + (e&7)] = bf16(C)
//
// Phase 2 (round-3 attn, verbatim): 1024 thr = 256 j x 4 e-quarters; L/a via
// wave-uniform global reads; R bf16 stream, depth-2 prefetch; 2 barriers.
// score[i][j] = 0.6*(uL[i]+uR[j]) + 0.4*sum_e a[e]*|L[i,e]+R[e,j]| + bias
// ---------------------------------------------------------------------------
__global__ __launch_bounds__(1024, 8) void fused_kernel(
    const float* __restrict__ x,      // (8,256,256) x[b][w][k]
    const float* __restrict__ W,      // (512,512)
    const float* __restrict__ b_lin,  // (512)
    const float* __restrict__ a,      // (512)
    const float* __restrict__ bias,   // (256,256)
    float* __restrict__ LpT,          // ws: (8,64,512,4) fp32 L^T blocked
    unsigned short* __restrict__ R2,  // ws: (8, 512e x 256j packed) bf16
    unsigned short* __restrict__ xbf, // ws: (8,256,256) bf16
    unsigned int* __restrict__ bar,   // ws: grid barrier counter (memset 0)
    float* __restrict__ out)          // (8,256,256)
{
    __shared__ union {
        struct {                                   // phase 1: 73728 B
            unsigned short As[4][64][72];
            unsigned short Bs[4][64][72];
        } g;
        struct {                                   // phase 2: ~29 KB
            float acc2P[4][4][256];
            float rgp[4][256];
            float u15p[8][4];
            unsigned short atbf[16 * 264];
        } s;
    } sh;

    const int tid = threadIdx.x;
    const int sub = tid >> 8;                      // 0..3
    const int t8  = tid & 255;                     // 0..255
    const int vb  = sub * 512 + (int)blockIdx.x;   // every block: sub0 = GEMM

    // =====================================================================
    // Phase 1
    // =====================================================================
    const bool isGemm = (vb < 512);
    const bool isConv = (vb >= 512) && (vb < 768);

    if (isConv) {   // ---- x -> bf16 straight conversion (no barriers inside)
        const int q   = vb - 512;
        const int cb  = q >> 5;
        const int ct  = q & 31;
        const int idx = cb * 65536 + ct * 2048 + t8 * 8;
        const float4 v0 = *(const float4*)(x + idx);
        const float4 v1 = *(const float4*)(x + idx + 4);
        u16x8 o;
        o[0] = f2bf(v0.x); o[1] = f2bf(v0.y); o[2] = f2bf(v0.z); o[3] = f2bf(v0.w);
        o[4] = f2bf(v1.x); o[5] = f2bf(v1.y); o[6] = f2bf(v1.z); o[7] = f2bf(v1.w);
        *(u16x8*)(xbf + idx) = o;
    }

    // GEMM job parameters (garbage-but-unused when !isGemm)
    int gb = 0, m0 = 0, n0 = 0;
    bool left = false;
    if (isGemm) {
        gb = vb >> 6;                              // batch 0..7
        const int t = vb & 63;
        left = (t < 32);
        if (left) { m0 = (t >> 3) * 64; n0 = (t & 7) * 64; }
        else      { const int tt = t - 32; m0 = (tt >> 2) * 64; n0 = (tt & 3) * 64; }
    }
    const int cbase = left ? m0 : n0;              // x column base (k or j)
    const int rbase = left ? n0 : m0;              // W row base (e)
    const int coff  = left ? 0 : 256;              // W column offset

    const int wv8  = t8 >> 6;                      // 0..3  (256-thr layout)
    const int ln8  = t8 & 63;
    const int wy = wv8 >> 1, wx = wv8 & 1;
    const int lr8 = ln8 & 15;
    const int lk8 = ln8 >> 4;
    const int wl = t8 >> 4;                        // 0..15
    const int kg = t8 & 15;                        // 0..15
    const int dr = t8 >> 2;                        // 0..63
    const int dc = (t8 & 3) * 16;

    const float* xb = x + gb * 65536;

    f32x4 acc[2][2];
    #pragma unroll
    for (int i = 0; i < 2; i++)
        #pragma unroll
        for (int jj = 0; jj < 2; jj++) acc[i][jj] = (f32x4){0.f, 0.f, 0.f, 0.f};

    unsigned short (*Ts)[72] = left ? sh.g.As[sub] : sh.g.Bs[sub];  // x^T tile
    unsigned short (*Ds)[72] = left ? sh.g.Bs[sub] : sh.g.As[sub];  // W tile
    unsigned short (*Asub)[72] = sh.g.As[sub];
    unsigned short (*Bsub)[72] = sh.g.Bs[sub];

    for (int k0 = 0; k0 < 256; k0 += 64) {
        if (isGemm) {
            #pragma unroll
            for (int p = 0; p < 4; p++) {
                const int w = wl + 16 * p;
                const float4 v = *(const float4*)(xb + (k0 + w) * 256 + cbase + kg * 4);
                Ts[kg * 4 + 0][w] = f2bf(v.x);
                Ts[kg * 4 + 1][w] = f2bf(v.y);
                Ts[kg * 4 + 2][w] = f2bf(v.z);
                Ts[kg * 4 + 3][w] = f2bf(v.w);
            }
            const float* src = W + (rbase + dr) * 512 + coff + k0 + dc;
            const float4 v0 = *(const float4*)(src);
            const float4 v1 = *(const float4*)(src + 4);
            const float4 v2 = *(const float4*)(src + 8);
            const float4 v3 = *(const float4*)(src + 12);
            u16x8 o0, o1;
            o0[0]=f2bf(v0.x); o0[1]=f2bf(v0.y); o0[2]=f2bf(v0.z); o0[3]=f2bf(v0.w);
            o0[4]=f2bf(v1.x); o0[5]=f2bf(v1.y); o0[6]=f2bf(v1.z); o0[7]=f2bf(v1.w);
            o1[0]=f2bf(v2.x); o1[1]=f2bf(v2.y); o1[2]=f2bf(v2.z); o1[3]=f2bf(v2.w);
            o1[4]=f2bf(v3.x); o1[5]=f2bf(v3.y); o1[6]=f2bf(v3.z); o1[7]=f2bf(v3.w);
            *(u16x8*)&Ds[dr][dc]     = o0;
            *(u16x8*)&Ds[dr][dc + 8] = o1;
        }
        __syncthreads();
        if (isGemm) {
            #pragma unroll
            for (int kk = 0; kk < 64; kk += 32) {
                const bf16x8 a0 = *(const bf16x8*)&Asub[wy * 32 + lr8][kk + lk8 * 8];
                const bf16x8 a1 = *(const bf16x8*)&Asub[wy * 32 + 16 + lr8][kk + lk8 * 8];
                const bf16x8 b0 = *(const bf16x8*)&Bsub[wx * 32 + lr8][kk + lk8 * 8];
                const bf16x8 b1 = *(const bf16x8*)&Bsub[wx * 32 + 16 + lr8][kk + lk8 * 8];
                acc[0][0] = __builtin_amdgcn_mfma_f32_16x16x32_bf16(a0, b0, acc[0][0], 0, 0, 0);
                acc[0][1] = __builtin_amdgcn_mfma_f32_16x16x32_bf16(a0, b1, acc[0][1], 0, 0, 0);
                acc[1][0] = __builtin_amdgcn_mfma_f32_16x16x32_bf16(a1, b0, acc[1][0], 0, 0, 0);
                acc[1][1] = __builtin_amdgcn_mfma_f32_16x16x32_bf16(a1, b1, acc[1][1], 0, 0, 0);
            }
        }
        __syncthreads();
    }

    if (isGemm) {
        // C/D layout: col = lane&15, row = (lane>>4)*4 + reg
        if (left) {
            #pragma unroll
            for (int mi = 0; mi < 2; mi++) {
                #pragma unroll
                for (int ni = 0; ni < 2; ni++) {
                    const int row = m0 + wy * 32 + mi * 16 + lk8 * 4;  // i (=k)
                    const int col = n0 + wx * 32 + ni * 16 + lr8;      // e
                    const float bl = b_lin[col];
                    float4 o;
                    o.x = acc[mi][ni][0] + bl;
                    o.y = acc[mi][ni][1] + bl;
                    o.z = acc[mi][ni][2] + bl;
                    o.w = acc[mi][ni][3] + bl;
                    *(float4*)(LpT + gb * 131072 + (row >> 2) * 2048 + col * 4) = o;
                }
            }
        } else {
            unsigned short* R2b = R2 + gb * 131072;
            #pragma unroll
            for (int mi = 0; mi < 2; mi++) {
                #pragma unroll
                for (int ni = 0; ni < 2; ni++) {
                    const int row = m0 + wy * 32 + mi * 16 + lk8 * 4;  // e base
                    const int col = n0 + wx * 32 + ni * 16 + lr8;      // j
                    ushort4 o;
                    o.x = f2bf(acc[mi][ni][0]);
                    o.y = f2bf(acc[mi][ni][1]);
                    o.z = f2bf(acc[mi][ni][2]);
                    o.w = f2bf(acc[mi][ni][3]);
                    *(ushort4*)(R2b + (row >> 3) * 2048 + col * 8 + (row & 7)) = o;
                }
            }
        }
    }

    // ---- hand-rolled grid barrier (device scope, cross-XCD per G16) ----
    __threadfence();                               // release all prior stores
    __syncthreads();
    if (tid == 0) {
        __hip_atomic_fetch_add(bar, 1u, __ATOMIC_ACQ_REL, __HIP_MEMORY_SCOPE_AGENT);
        while (__hip_atomic_load(bar, __ATOMIC_ACQUIRE, __HIP_MEMORY_SCOPE_AGENT) < 512u)
            __builtin_amdgcn_s_sleep(16);
    }
    __syncthreads();
    __threadfence();                               // acquire: invalidate stale

    // =====================================================================
    // Phase 2 (round-3 attn, verbatim structure)
    // =====================================================================
    const int b     = (int)blockIdx.x & 7;
    const int itile = (int)blockIdx.x >> 3;        // 0..63
    const int i0    = itile * 4;
    const int j     = tid & 255;
    const int wv    = tid >> 6;                    // 0..15
    const int lane  = tid & 63;

    // wave-uniform e-quarter index (readfirstlane -> SGPR)
    const int ehq = __builtin_amdgcn_readfirstlane(sub);   // 0..3

    // uniform stream bases
    const float* Lq = LpT + b * 131072 + itile * 2048 + ehq * 512;  // [e_loc][4]
    const float* aq = a + ehq * 128;
    const unsigned int* R2u = (const unsigned int*)R2;
    const uint4* Rq = (const uint4*)(R2u + b * 65536) + (ehq * 16) * 256 + j;

    // ---- R prefetch, depth 2 (named regs, no dynamic indexing)
    uint4 rb0 = Rq[0];
    uint4 rb1 = Rq[256];

    // ---- uL partials: waves 0..7; waves 8..15 go straight to score
    if (tid < 512) {
        const float4 lv = *(const float4*)(LpT + b * 131072 + itile * 2048 + tid * 4);
        const float ae = a[tid];
        float p0 = ae * lv.x, p1 = ae * lv.y, p2 = ae * lv.z, p3 = ae * lv.w;
        #pragma unroll
        for (int off = 32; off; off >>= 1) {
            p0 += __shfl_xor(p0, off);
            p1 += __shfl_xor(p1, off);
            p2 += __shfl_xor(p2, off);
            p3 += __shfl_xor(p3, off);
        }
        if (lane == 0) {
            sh.s.u15p[wv][0] = p0; sh.s.u15p[wv][1] = p1;
            sh.s.u15p[wv][2] = p2; sh.s.u15p[wv][3] = p3;
        }
    }

    // ---- score: 128 e per thread (e-quarter), 4 i rows, uniform L/a loads
    float acc0 = 0.f, acc1 = 0.f, acc2 = 0.f, acc3 = 0.f, rsum = 0.f;

    #pragma unroll 2
    for (int tk = 0; tk < 16; tk++) {
        uint4 rb2;
        if (tk < 14) rb2 = Rq[(tk + 2) * 256];
        float r[8];
        r[0] = bf_lo(rb0.x); r[1] = bf_hi(rb0.x);
        r[2] = bf_lo(rb0.y); r[3] = bf_hi(rb0.y);
        r[4] = bf_lo(rb0.z); r[5] = bf_hi(rb0.z);
        r[6] = bf_lo(rb0.w); r[7] = bf_hi(rb0.w);
        #pragma unroll
        for (int g = 0; g < 2; g++) {
            const float4 av4 = *(const float4*)(aq + tk * 8 + g * 4);
            const float4 l0 = *(const float4*)(Lq + (tk * 8 + g * 4 + 0) * 4);
            const float4 l1 = *(const float4*)(Lq + (tk * 8 + g * 4 + 1) * 4);
            const float4 l2 = *(const float4*)(Lq + (tk * 8 + g * 4 + 2) * 4);
            const float4 l3 = *(const float4*)(Lq + (tk * 8 + g * 4 + 3) * 4);
            const float rv0 = r[g * 4 + 0];
            const float rv1 = r[g * 4 + 1];
            const float rv2 = r[g * 4 + 2];
            const float rv3 = r[g * 4 + 3];
            rsum = fmaf(av4.x, rv0, rsum);
            acc0 = fmaf(av4.x, fabsf(l0.x + rv0), acc0);
            acc1 = fmaf(av4.x, fabsf(l0.y + rv0), acc1);
            acc2 = fmaf(av4.x, fabsf(l0.z + rv0), acc2);
            acc3 = fmaf(av4.x, fabsf(l0.w + rv0), acc3);
            rsum = fmaf(av4.y, rv1, rsum);
            acc0 = fmaf(av4.y, fabsf(l1.x + rv1), acc0);
            acc1 = fmaf(av4.y, fabsf(l1.y + rv1), acc1);
            acc2 = fmaf(av4.y, fabsf(l1.z + rv1), acc2);
            acc3 = fmaf(av4.y, fabsf(l1.w + rv1), acc3);
            rsum = fmaf(av4.z, rv2, rsum);
            acc0 = fmaf(av4.z, fabsf(l2.x + rv2), acc0);
            acc1 = fmaf(av4.z, fabsf(l2.y + rv2), acc1);
            acc2 = fmaf(av4.z, fabsf(l2.z + rv2), acc2);
            acc3 = fmaf(av4.z, fabsf(l2.w + rv2), acc3);
            rsum = fmaf(av4.w, rv3, rsum);
            acc0 = fmaf(av4.w, fabsf(l3.x + rv3), acc0);
            acc1 = fmaf(av4.w, fabsf(l3.y + rv3), acc1);
            acc2 = fmaf(av4.w, fabsf(l3.z + rv3), acc2);
            acc3 = fmaf(av4.w, fabsf(l3.w + rv3), acc3);
        }
        rb0 = rb1;
        rb1 = rb2;
    }
    sh.s.acc2P[ehq][0][j] = acc0;
    sh.s.acc2P[ehq][1][j] = acc1;
    sh.s.acc2P[ehq][2][j] = acc2;
    sh.s.acc2P[ehq][3][j] = acc3;
    sh.s.rgp[ehq][j] = rsum;
    __syncthreads();

    // ---- softmax (combine folded in): wave i (wv<4) -> row i
    if (wv < 4) {
        const int i = wv;
        float u15 = 0.f;
        #pragma unroll
        for (int q = 0; q < 8; q++) u15 += sh.s.u15p[q][i];
        u15 *= 0.6f;
        float v[4];
        float m = -1e30f;
        #pragma unroll
        for (int u = 0; u < 4; u++) {
            const int jj = lane + 64 * u;
            const float uR = sh.s.rgp[0][jj] + sh.s.rgp[1][jj]
                           + sh.s.rgp[2][jj] + sh.s.rgp[3][jj];
            const float ab = sh.s.acc2P[0][i][jj] + sh.s.acc2P[1][i][jj]
                           + sh.s.acc2P[2][i][jj] + sh.s.acc2P[3][i][jj];
            v[u] = u15 + 0.6f * uR + 0.4f * ab + bias[(i0 + i) * 256 + jj];
            m = fmaxf(m, v[u]);
        }
        #pragma unroll
        for (int off = 32; off; off >>= 1) m = fmaxf(m, __shfl_xor(m, off));
        float ssum = 0.f;
        #pragma unroll
        for (int u = 0; u < 4; u++) { v[u] = __expf(v[u] - m); ssum += v[u]; }
        #pragma unroll
        for (int off = 32; off; off >>= 1) ssum += __shfl_xor(ssum, off);
        const float inv = 1.f / ssum;
        #pragma unroll
        for (int u = 0; u < 4; u++)
            sh.s.atbf[i * 264 + lane + 64 * u] = f2bf(v[u] * inv);
    }
    __syncthreads();

    // ---- matvec via MFMA: D[i][w] = sum_j attn[i][j] * x[b][w][j]
    // 16 waves; wave wv handles w-tile wv. A rows 4..15 are garbage LDS but
    // only pollute D rows 4..15, which are never stored (lk==0 only).
    {
        const int lr = lane & 15;
        const int lk = lane >> 4;
        f32x4 hacc = (f32x4){0.f, 0.f, 0.f, 0.f};
        const unsigned short* xw = xbf + b * 65536 + (wv * 16 + lr) * 256;
        #pragma unroll
        for (int kt = 0; kt < 8; kt++) {
            const bf16x8 av = *(const bf16x8*)&sh.s.atbf[lr * 264 + kt * 32 + lk * 8];
            const bf16x8 bv = *(const bf16x8*)(xw + kt * 32 + lk * 8);
            hacc = __builtin_amdgcn_mfma_f32_16x16x32_bf16(av, bv, hacc, 0, 0, 0);
        }
        if (lk == 0) {
            float4 o;
            o.x = sigmoidf_(hacc[0]);
            o.y = sigmoidf_(hacc[1]);
            o.z = sigmoidf_(hacc[2]);
            o.w = sigmoidf_(hacc[3]);
            *(float4*)(out + b * 65536 + (wv * 16 + lr) * 256 + i0) = o;
        }
    }
}

extern "C" void kernel_launch(void* const* d_in, const int* in_sizes, int n_in,
                              void* d_out, int out_size, void* d_ws, size_t ws_size,
                              hipStream_t stream) {
    const float* x     = (const float*)d_in[0];
    const float* W     = (const float*)d_in[1];
    const float* b_lin = (const float*)d_in[2];
    const float* a     = (const float*)d_in[3];
    const float* bias  = (const float*)d_in[4];
    float* out = (float*)d_out;

    char* ws = (char*)d_ws;
    float*          LpT = (float*)ws;                          // 4 MB
    unsigned short* R2  = (unsigned short*)(ws + (4 << 20));   // 2 MB
    unsigned short* xbf = (unsigned short*)(ws + (6 << 20));   // 1 MB
    unsigned int*   bar = (unsigned int*)(ws + (7 << 20));     // 64 B

    hipMemsetAsync(bar, 0, 64, stream);   // stream-ordered, capture-legal
    hipLaunchKernelGGL(fused_kernel, dim3(512), dim3(1024), 0, stream,
                       x, W, b_lin, a, bias, LpT, R2, xbf, bar, out);
}

// Round 7
// 433.913 us; speedup vs baseline: 1.1144x; 1.1144x over previous
//
#include <hip/hip_runtime.h>
#include <math.h>

typedef float f32x4 __attribute__((ext_vector_type(4)));
typedef __bf16 bf16x8 __attribute__((ext_vector_type(8)));
typedef unsigned short u16x8 __attribute__((ext_vector_type(8)));

__device__ __forceinline__ unsigned short f2bf(float f) {
    __bf16 h = (__bf16)f;                 // native v_cvt (RNE), pairs fuse to
    unsigned short u;                     // v_cvt_pk_bf16_f32
    __builtin_memcpy(&u, &h, 2);
    return u;
}
__device__ __forceinline__ float bf_lo(unsigned int d) {
    union { unsigned int u; float f; } v; v.u = d << 16; return v.f;
}
__device__ __forceinline__ float bf_hi(unsigned int d) {
    union { unsigned int u; float f; } v; v.u = d & 0xffff0000u; return v.f;
}
__device__ __forceinline__ float sigmoidf_(float v) {
    return 1.f / (1.f + __expf(-v));
}

// ---------------------------------------------------------------------------
// Kernel 1 (verbatim round-3, the proven config): fused convert + MFMA bf16
// GEMM + x->bf16 conversion.
//  left  (t<32):  -> LpT[b][i>>2][e][i&3] = C + b_lin[e]   (fp32 transposed)
//  right (32<=t<64): -> R2[b][(e>>3)*2048 + j*8 + (e&7)] = bf16(C)
//  conv  (t>=64): xbf = bf16(x)
// ---------------------------------------------------------------------------
__global__ __launch_bounds__(256) void mfma_gemm_kernel(
    const float* __restrict__ x,      // (8,256,256) x[b][w][k]
    const float* __restrict__ W,      // (512,512)
    const float* __restrict__ b_lin,  // (512)
    float* __restrict__ LpT,          // (8,64,512,4) fp32  L^T blocked
    unsigned short* __restrict__ R2,  // (8, 512e x 256j packed)
    unsigned short* __restrict__ xbf) // (8,256,256) bf16
{
    const int b = blockIdx.y;
    const int t = blockIdx.x;

    if (t >= 64) {   // ---- x -> bf16 straight conversion
        const int idx = b * 65536 + (t - 64) * 2048 + threadIdx.x * 8;
        const float4 v0 = *(const float4*)(x + idx);
        const float4 v1 = *(const float4*)(x + idx + 4);
        u16x8 o;
        o[0] = f2bf(v0.x); o[1] = f2bf(v0.y); o[2] = f2bf(v0.z); o[3] = f2bf(v0.w);
        o[4] = f2bf(v1.x); o[5] = f2bf(v1.y); o[6] = f2bf(v1.z); o[7] = f2bf(v1.w);
        *(u16x8*)(xbf + idx) = o;
        return;
    }

    const bool left = (t < 32);
    int m0, n0;
    if (left) { m0 = (t >> 3) * 64; n0 = (t & 7) * 64; }
    else      { const int tt = t - 32; m0 = (tt >> 2) * 64; n0 = (tt & 3) * 64; }

    __shared__ unsigned short As[64][72];
    __shared__ unsigned short Bs[64][72];

    unsigned short (*Ts)[72] = left ? As : Bs;   // x^T tile
    unsigned short (*Ds)[72] = left ? Bs : As;   // W tile
    const int cbase = left ? m0 : n0;            // x column base (k or j)
    const int rbase = left ? n0 : m0;            // W row base (e)
    const int coff  = left ? 0 : 256;            // W column offset

    const int tid  = threadIdx.x;
    const int wv   = tid >> 6;
    const int lane = tid & 63;
    const int wy = wv >> 1, wx = wv & 1;
    const int lr = lane & 15;
    const int lk = lane >> 4;

    const float* xb = x + b * 65536;

    f32x4 acc[2][2];
    #pragma unroll
    for (int i = 0; i < 2; i++)
        #pragma unroll
        for (int jj = 0; jj < 2; jj++) acc[i][jj] = (f32x4){0.f, 0.f, 0.f, 0.f};

    const int wl = tid >> 4;         // 0..15
    const int kg = tid & 15;         // 0..15
    const int dr = tid >> 2;         // 0..63
    const int dc = (tid & 3) * 16;

    for (int k0 = 0; k0 < 256; k0 += 64) {
        #pragma unroll
        for (int p = 0; p < 4; p++) {
            const int w = wl + 16 * p;
            const float4 v = *(const float4*)(xb + (k0 + w) * 256 + cbase + kg * 4);
            Ts[kg * 4 + 0][w] = f2bf(v.x);
            Ts[kg * 4 + 1][w] = f2bf(v.y);
            Ts[kg * 4 + 2][w] = f2bf(v.z);
            Ts[kg * 4 + 3][w] = f2bf(v.w);
        }
        {
            const float* src = W + (rbase + dr) * 512 + coff + k0 + dc;
            const float4 v0 = *(const float4*)(src);
            const float4 v1 = *(const float4*)(src + 4);
            const float4 v2 = *(const float4*)(src + 8);
            const float4 v3 = *(const float4*)(src + 12);
            u16x8 o0, o1;
            o0[0]=f2bf(v0.x); o0[1]=f2bf(v0.y); o0[2]=f2bf(v0.z); o0[3]=f2bf(v0.w);
            o0[4]=f2bf(v1.x); o0[5]=f2bf(v1.y); o0[6]=f2bf(v1.z); o0[7]=f2bf(v1.w);
            o1[0]=f2bf(v2.x); o1[1]=f2bf(v2.y); o1[2]=f2bf(v2.z); o1[3]=f2bf(v2.w);
            o1[4]=f2bf(v3.x); o1[5]=f2bf(v3.y); o1[6]=f2bf(v3.z); o1[7]=f2bf(v3.w);
            *(u16x8*)&Ds[dr][dc]     = o0;
            *(u16x8*)&Ds[dr][dc + 8] = o1;
        }
        __syncthreads();
        #pragma unroll
        for (int kk = 0; kk < 64; kk += 32) {
            const bf16x8 a0 = *(const bf16x8*)&As[wy * 32 + lr][kk + lk * 8];
            const bf16x8 a1 = *(const bf16x8*)&As[wy * 32 + 16 + lr][kk + lk * 8];
            const bf16x8 b0 = *(const bf16x8*)&Bs[wx * 32 + lr][kk + lk * 8];
            const bf16x8 b1 = *(const bf16x8*)&Bs[wx * 32 + 16 + lr][kk + lk * 8];
            acc[0][0] = __builtin_amdgcn_mfma_f32_16x16x32_bf16(a0, b0, acc[0][0], 0, 0, 0);
            acc[0][1] = __builtin_amdgcn_mfma_f32_16x16x32_bf16(a0, b1, acc[0][1], 0, 0, 0);
            acc[1][0] = __builtin_amdgcn_mfma_f32_16x16x32_bf16(a1, b0, acc[1][0], 0, 0, 0);
            acc[1][1] = __builtin_amdgcn_mfma_f32_16x16x32_bf16(a1, b1, acc[1][1], 0, 0, 0);
        }
        __syncthreads();
    }

    // C/D layout: col = lane&15, row = (lane>>4)*4 + reg
    if (left) {
        #pragma unroll
        for (int mi = 0; mi < 2; mi++) {
            #pragma unroll
            for (int ni = 0; ni < 2; ni++) {
                const int row = m0 + wy * 32 + mi * 16 + lk * 4;   // i (=k)
                const int col = n0 + wx * 32 + ni * 16 + lr;       // e
                const float bl = b_lin[col];
                float4 o;
                o.x = acc[mi][ni][0] + bl;
                o.y = acc[mi][ni][1] + bl;
                o.z = acc[mi][ni][2] + bl;
                o.w = acc[mi][ni][3] + bl;
                *(float4*)(LpT + b * 131072 + (row >> 2) * 2048 + col * 4) = o;
            }
        }
    } else {
        unsigned short* R2b = R2 + b * 131072;
        #pragma unroll
        for (int mi = 0; mi < 2; mi++) {
            #pragma unroll
            for (int ni = 0; ni < 2; ni++) {
                const int row = m0 + wy * 32 + mi * 16 + lk * 4;   // e base (4)
                const int col = n0 + wx * 32 + ni * 16 + lr;       // j
                ushort4 o;
                o.x = f2bf(acc[mi][ni][0]);
                o.y = f2bf(acc[mi][ni][1]);
                o.z = f2bf(acc[mi][ni][2]);
                o.w = f2bf(acc[mi][ni][3]);
                *(ushort4*)(R2b + (row >> 3) * 2048 + col * 8 + (row & 7)) = o;
            }
        }
    }
}

// ---------------------------------------------------------------------------
// Kernel 2: split-e attention with deterministic last-block combine.
// grid 1024 = (itile 0..63) x (e-half h) x (b = blk&7); 1024 thr = 256 j x
// 4 e-16ths. Each block scores 256 of the 512 e (64 e/thread), writes a 5KB
// partial {ab[4][256], uR[256], uL[4]} + one bounded ACQ_REL/AGENT ticket.
// First arriver EXITS (frees wave slots -> next block generation's score
// overlaps this generation's softmax/matvec); second arriver combines
// (fixed pb0+pb1 order -> deterministic), softmaxes, matvecs.
// No spinning anywhere (r6 post-mortem: spin acquires = L2-invalidate storm).
// score[i][j] = 0.6*(uL[i]+uR[j]) + 0.4*sum_e a[e]*|L[i,e]+R[e,j]| + bias
// ---------------------------------------------------------------------------
__global__ __launch_bounds__(1024, 8) void attn_kernel(
    const unsigned short* __restrict__ xbf,   // (8,256,256) bf16 x[b][w][j]
    const float* __restrict__ LpT,            // (8,64,512,4) fp32, b_lin folded
    const unsigned int* __restrict__ R2u,     // packed bf16 pairs
    const float* __restrict__ a,              // (512)
    const float* __restrict__ bias,           // (256,256)
    float* __restrict__ pbuf,                 // ws: 1024 x 1284 fp32 partials
    unsigned int* __restrict__ tickets,       // ws: 512, memset 0 per launch
    float* __restrict__ out)                  // (8,256,256)
{
    const int blk   = (int)blockIdx.x;
    const int b     = blk & 7;                // XCD-local heuristic (perf only)
    const int h     = (blk >> 3) & 1;         // e-half
    const int itile = blk >> 4;               // 0..63
    const int p     = itile * 8 + b;          // pair id 0..511
    const int i0    = itile * 4;
    const int tid   = threadIdx.x;
    const int j     = tid & 255;
    const int wv    = tid >> 6;               // 0..15
    const int lane  = tid & 63;

    __shared__ float acc2P[4][4][256];        // 16 KB [e-16th][i][j]
    __shared__ float rgp[4][256];             // 4 KB
    __shared__ float u15p[4][4];
    __shared__ unsigned short atbf[16 * 264]; // 8.25 KB
    __shared__ unsigned int lastf;

    // wave-uniform e-16th index
    const int sq = __builtin_amdgcn_readfirstlane(tid >> 8);   // 0..3
    const int e0 = h * 256 + sq * 64;         // global e base for this sq

    // uniform stream bases
    const float* Lq = LpT + b * 131072 + itile * 2048 + e0 * 4;  // [e_loc][4]
    const float* aq = a + e0;
    const uint4* Rq = (const uint4*)(R2u + b * 65536) + (e0 >> 3) * 256 + j;

    // ---- R prefetch, depth 2 (named regs)
    uint4 rb0 = Rq[0];
    uint4 rb1 = Rq[256];

    // ---- uL partials over THIS block's e-half: waves 0..3, e = h*256+tid
    if (tid < 256) {
        const int e = h * 256 + tid;
        const float4 lv = *(const float4*)(LpT + b * 131072 + itile * 2048 + e * 4);
        const float ae = a[e];
        float p0 = ae * lv.x, p1 = ae * lv.y, p2 = ae * lv.z, p3 = ae * lv.w;
        #pragma unroll
        for (int off = 32; off; off >>= 1) {
            p0 += __shfl_xor(p0, off);
            p1 += __shfl_xor(p1, off);
            p2 += __shfl_xor(p2, off);
            p3 += __shfl_xor(p3, off);
        }
        if (lane == 0) {
            u15p[wv][0] = p0; u15p[wv][1] = p1;
            u15p[wv][2] = p2; u15p[wv][3] = p3;
        }
    }

    // ---- score: 64 e per thread (8 tk), 4 i rows, uniform L/a loads
    float acc0 = 0.f, acc1 = 0.f, acc2 = 0.f, acc3 = 0.f, rsum = 0.f;

    #pragma unroll 2
    for (int tk = 0; tk < 8; tk++) {
        uint4 rb2;
        if (tk < 6) rb2 = Rq[(tk + 2) * 256];
        float r[8];
        r[0] = bf_lo(rb0.x); r[1] = bf_hi(rb0.x);
        r[2] = bf_lo(rb0.y); r[3] = bf_hi(rb0.y);
        r[4] = bf_lo(rb0.z); r[5] = bf_hi(rb0.z);
        r[6] = bf_lo(rb0.w); r[7] = bf_hi(rb0.w);
        #pragma unroll
        for (int g = 0; g < 2; g++) {
            const float4 av4 = *(const float4*)(aq + tk * 8 + g * 4);
            const float4 l0 = *(const float4*)(Lq + (tk * 8 + g * 4 + 0) * 4);
            const float4 l1 = *(const float4*)(Lq + (tk * 8 + g * 4 + 1) * 4);
            const float4 l2 = *(const float4*)(Lq + (tk * 8 + g * 4 + 2) * 4);
            const float4 l3 = *(const float4*)(Lq + (tk * 8 + g * 4 + 3) * 4);
            const float rv0 = r[g * 4 + 0];
            const float rv1 = r[g * 4 + 1];
            const float rv2 = r[g * 4 + 2];
            const float rv3 = r[g * 4 + 3];
            rsum = fmaf(av4.x, rv0, rsum);
            acc0 = fmaf(av4.x, fabsf(l0.x + rv0), acc0);
            acc1 = fmaf(av4.x, fabsf(l0.y + rv0), acc1);
            acc2 = fmaf(av4.x, fabsf(l0.z + rv0), acc2);
            acc3 = fmaf(av4.x, fabsf(l0.w + rv0), acc3);
            rsum = fmaf(av4.y, rv1, rsum);
            acc0 = fmaf(av4.y, fabsf(l1.x + rv1), acc0);
            acc1 = fmaf(av4.y, fabsf(l1.y + rv1), acc1);
            acc2 = fmaf(av4.y, fabsf(l1.z + rv1), acc2);
            acc3 = fmaf(av4.y, fabsf(l1.w + rv1), acc3);
            rsum = fmaf(av4.z, rv2, rsum);
            acc0 = fmaf(av4.z, fabsf(l2.x + rv2), acc0);
            acc1 = fmaf(av4.z, fabsf(l2.y + rv2), acc1);
            acc2 = fmaf(av4.z, fabsf(l2.z + rv2), acc2);
            acc3 = fmaf(av4.z, fabsf(l2.w + rv2), acc3);
            rsum = fmaf(av4.w, rv3, rsum);
            acc0 = fmaf(av4.w, fabsf(l3.x + rv3), acc0);
            acc1 = fmaf(av4.w, fabsf(l3.y + rv3), acc1);
            acc2 = fmaf(av4.w, fabsf(l3.z + rv3), acc2);
            acc3 = fmaf(av4.w, fabsf(l3.w + rv3), acc3);
        }
        rb0 = rb1;
        rb1 = rb2;
    }
    acc2P[sq][0][j] = acc0;
    acc2P[sq][1][j] = acc1;
    acc2P[sq][2][j] = acc2;
    acc2P[sq][3][j] = acc3;
    rgp[sq][j] = rsum;
    __syncthreads();

    // ---- write this block's partial: ab[4][256] + uR[256] + uL[4]
    {
        const int ci = tid >> 8, cj = tid & 255;
        float* pb = pbuf + (p * 2 + h) * 1284;
        pb[ci * 256 + cj] = acc2P[0][ci][cj] + acc2P[1][ci][cj]
                          + acc2P[2][ci][cj] + acc2P[3][ci][cj];
        if (ci == 0)
            pb[1024 + cj] = rgp[0][cj] + rgp[1][cj] + rgp[2][cj] + rgp[3][cj];
        if (tid < 4)
            pb[1280 + tid] = u15p[0][tid] + u15p[1][tid]
                           + u15p[2][tid] + u15p[3][tid];
    }
    __threadfence();                      // release partial stores (bounded)
    __syncthreads();
    if (tid == 0)
        lastf = __hip_atomic_fetch_add(&tickets[p], 1u,
                                       __ATOMIC_ACQ_REL,
                                       __HIP_MEMORY_SCOPE_AGENT);
    __syncthreads();
    if (lastf == 0) return;               // first arriver: done (early exit)

    // =====================================================================
    // Last arriver: combine partials (fixed order -> deterministic),
    // softmax, matvec.
    // =====================================================================
    const float* pb0 = pbuf + (p * 2 + 0) * 1284;
    const float* pb1 = pbuf + (p * 2 + 1) * 1284;

    if (wv < 4) {
        const int i = wv;
        const float u15 = 0.6f * (pb0[1280 + i] + pb1[1280 + i]);
        float v[4];
        float m = -1e30f;
        #pragma unroll
        for (int u = 0; u < 4; u++) {
            const int jj = lane + 64 * u;
            const float uR = pb0[1024 + jj] + pb1[1024 + jj];
            const float ab = pb0[i * 256 + jj] + pb1[i * 256 + jj];
            v[u] = u15 + 0.6f * uR + 0.4f * ab + bias[(i0 + i) * 256 + jj];
            m = fmaxf(m, v[u]);
        }
        #pragma unroll
        for (int off = 32; off; off >>= 1) m = fmaxf(m, __shfl_xor(m, off));
        float ssum = 0.f;
        #pragma unroll
        for (int u = 0; u < 4; u++) { v[u] = __expf(v[u] - m); ssum += v[u]; }
        #pragma unroll
        for (int off = 32; off; off >>= 1) ssum += __shfl_xor(ssum, off);
        const float inv = 1.f / ssum;
        #pragma unroll
        for (int u = 0; u < 4; u++)
            atbf[i * 264 + lane + 64 * u] = f2bf(v[u] * inv);
    }
    __syncthreads();

    // ---- matvec via MFMA: D[i][w] = sum_j attn[i][j] * x[b][w][j]
    {
        const int lr = lane & 15;
        const int lk = lane >> 4;
        f32x4 hacc = (f32x4){0.f, 0.f, 0.f, 0.f};
        const unsigned short* xw = xbf + b * 65536 + (wv * 16 + lr) * 256;
        #pragma unroll
        for (int kt = 0; kt < 8; kt++) {
            const bf16x8 av = *(const bf16x8*)&atbf[lr * 264 + kt * 32 + lk * 8];
            const bf16x8 bv = *(const bf16x8*)(xw + kt * 32 + lk * 8);
            hacc = __builtin_amdgcn_mfma_f32_16x16x32_bf16(av, bv, hacc, 0, 0, 0);
        }
        if (lk == 0) {
            float4 o;
            o.x = sigmoidf_(hacc[0]);
            o.y = sigmoidf_(hacc[1]);
            o.z = sigmoidf_(hacc[2]);
            o.w = sigmoidf_(hacc[3]);
            *(float4*)(out + b * 65536 + (wv * 16 + lr) * 256 + i0) = o;
        }
    }
}

extern "C" void kernel_launch(void* const* d_in, const int* in_sizes, int n_in,
                              void* d_out, int out_size, void* d_ws, size_t ws_size,
                              hipStream_t stream) {
    const float* x     = (const float*)d_in[0];
    const float* W     = (const float*)d_in[1];
    const float* b_lin = (const float*)d_in[2];
    const float* a     = (const float*)d_in[3];
    const float* bias  = (const float*)d_in[4];
    float* out = (float*)d_out;

    char* ws = (char*)d_ws;
    float*          LpT     = (float*)ws;                          // 4 MB
    unsigned short* R2      = (unsigned short*)(ws + (4 << 20));   // 2 MB
    unsigned short* xbf     = (unsigned short*)(ws + (6 << 20));   // 1 MB
    float*          pbuf    = (float*)(ws + (8 << 20));            // ~5 MB
    unsigned int*   tickets = (unsigned int*)(ws + (14 << 20));    // 2 KB

    hipMemsetAsync(tickets, 0, 512 * sizeof(unsigned int), stream);
    mfma_gemm_kernel<<<dim3(96, 8), 256, 0, stream>>>(x, W, b_lin, LpT, R2, xbf);
    attn_kernel<<<1024, 1024, 0, stream>>>(xbf, LpT, (const unsigned int*)R2,
                                           a, bias, pbuf, tickets, out);
}

// Round 8
// 109.785 us; speedup vs baseline: 4.4046x; 3.9524x over previous
//
#include <hip/hip_runtime.h>
#include <math.h>

typedef float f32x4 __attribute__((ext_vector_type(4)));
typedef __bf16 bf16x8 __attribute__((ext_vector_type(8)));
typedef unsigned short u16x8 __attribute__((ext_vector_type(8)));

__device__ __forceinline__ unsigned short f2bf(float f) {
    union { float f; unsigned int u; } v; v.f = f;
    unsigned int u = v.u;
    return (unsigned short)((u + 0x7fffu + ((u >> 16) & 1u)) >> 16);  // RNE
}
__device__ __forceinline__ float bf_lo(unsigned int d) {
    union { unsigned int u; float f; } v; v.u = d << 16; return v.f;
}
__device__ __forceinline__ float bf_hi(unsigned int d) {
    union { unsigned int u; float f; } v; v.u = d & 0xffff0000u; return v.f;
}
__device__ __forceinline__ float sigmoidf_(float v) {
    return 1.f / (1.f + __expf(-v));
}

// ---------------------------------------------------------------------------
// Kernel 1 (exact r1-bench version, proven 101.2/102.2): fused convert +
// MFMA bf16 GEMM + x->bf16 conversion.
//  left  (t<32):  -> LpT[b][i>>2][e][i&3] = C + b_lin[e]   (fp32 transposed)
//  right (32<=t<64): -> R2[b][(e>>3)*2048 + j*8 + (e&7)] = bf16(C)
//  conv  (t>=64): xbf = bf16(x)
// ---------------------------------------------------------------------------
__global__ __launch_bounds__(256) void mfma_gemm_kernel(
    const float* __restrict__ x,      // (8,256,256) x[b][w][k]
    const float* __restrict__ W,      // (512,512)
    const float* __restrict__ b_lin,  // (512)
    float* __restrict__ LpT,          // (8,64,512,4) fp32  L^T blocked
    unsigned short* __restrict__ R2,  // (8, 512e x 256j packed)
    unsigned short* __restrict__ xbf) // (8,256,256) bf16
{
    const int b = blockIdx.y;
    const int t = blockIdx.x;

    if (t >= 64) {   // ---- x -> bf16 straight conversion
        const int idx = b * 65536 + (t - 64) * 2048 + threadIdx.x * 8;
        const float4 v0 = *(const float4*)(x + idx);
        const float4 v1 = *(const float4*)(x + idx + 4);
        u16x8 o;
        o[0] = f2bf(v0.x); o[1] = f2bf(v0.y); o[2] = f2bf(v0.z); o[3] = f2bf(v0.w);
        o[4] = f2bf(v1.x); o[5] = f2bf(v1.y); o[6] = f2bf(v1.z); o[7] = f2bf(v1.w);
        *(u16x8*)(xbf + idx) = o;
        return;
    }

    const bool left = (t < 32);
    int m0, n0;
    if (left) { m0 = (t >> 3) * 64; n0 = (t & 7) * 64; }
    else      { const int tt = t - 32; m0 = (tt >> 2) * 64; n0 = (tt & 3) * 64; }

    __shared__ unsigned short As[64][72];
    __shared__ unsigned short Bs[64][72];

    unsigned short (*Ts)[72] = left ? As : Bs;   // x^T tile
    unsigned short (*Ds)[72] = left ? Bs : As;   // W tile
    const int cbase = left ? m0 : n0;            // x column base (k or j)
    const int rbase = left ? n0 : m0;            // W row base (e)
    const int coff  = left ? 0 : 256;            // W column offset

    const int tid  = threadIdx.x;
    const int wv   = tid >> 6;
    const int lane = tid & 63;
    const int wy = wv >> 1, wx = wv & 1;
    const int lr = lane & 15;
    const int lk = lane >> 4;

    const float* xb = x + b * 65536;

    f32x4 acc[2][2];
    #pragma unroll
    for (int i = 0; i < 2; i++)
        #pragma unroll
        for (int jj = 0; jj < 2; jj++) acc[i][jj] = (f32x4){0.f, 0.f, 0.f, 0.f};

    const int wl = tid >> 4;         // 0..15
    const int kg = tid & 15;         // 0..15
    const int dr = tid >> 2;         // 0..63
    const int dc = (tid & 3) * 16;

    for (int k0 = 0; k0 < 256; k0 += 64) {
        #pragma unroll
        for (int p = 0; p < 4; p++) {
            const int w = wl + 16 * p;
            const float4 v = *(const float4*)(xb + (k0 + w) * 256 + cbase + kg * 4);
            Ts[kg * 4 + 0][w] = f2bf(v.x);
            Ts[kg * 4 + 1][w] = f2bf(v.y);
            Ts[kg * 4 + 2][w] = f2bf(v.z);
            Ts[kg * 4 + 3][w] = f2bf(v.w);
        }
        {
            const float* src = W + (rbase + dr) * 512 + coff + k0 + dc;
            const float4 v0 = *(const float4*)(src);
            const float4 v1 = *(const float4*)(src + 4);
            const float4 v2 = *(const float4*)(src + 8);
            const float4 v3 = *(const float4*)(src + 12);
            u16x8 o0, o1;
            o0[0]=f2bf(v0.x); o0[1]=f2bf(v0.y); o0[2]=f2bf(v0.z); o0[3]=f2bf(v0.w);
            o0[4]=f2bf(v1.x); o0[5]=f2bf(v1.y); o0[6]=f2bf(v1.z); o0[7]=f2bf(v1.w);
            o1[0]=f2bf(v2.x); o1[1]=f2bf(v2.y); o1[2]=f2bf(v2.z); o1[3]=f2bf(v2.w);
            o1[4]=f2bf(v3.x); o1[5]=f2bf(v3.y); o1[6]=f2bf(v3.z); o1[7]=f2bf(v3.w);
            *(u16x8*)&Ds[dr][dc]     = o0;
            *(u16x8*)&Ds[dr][dc + 8] = o1;
        }
        __syncthreads();
        #pragma unroll
        for (int kk = 0; kk < 64; kk += 32) {
            const bf16x8 a0 = *(const bf16x8*)&As[wy * 32 + lr][kk + lk * 8];
            const bf16x8 a1 = *(const bf16x8*)&As[wy * 32 + 16 + lr][kk + lk * 8];
            const bf16x8 b0 = *(const bf16x8*)&Bs[wx * 32 + lr][kk + lk * 8];
            const bf16x8 b1 = *(const bf16x8*)&Bs[wx * 32 + 16 + lr][kk + lk * 8];
            acc[0][0] = __builtin_amdgcn_mfma_f32_16x16x32_bf16(a0, b0, acc[0][0], 0, 0, 0);
            acc[0][1] = __builtin_amdgcn_mfma_f32_16x16x32_bf16(a0, b1, acc[0][1], 0, 0, 0);
            acc[1][0] = __builtin_amdgcn_mfma_f32_16x16x32_bf16(a1, b0, acc[1][0], 0, 0, 0);
            acc[1][1] = __builtin_amdgcn_mfma_f32_16x16x32_bf16(a1, b1, acc[1][1], 0, 0, 0);
        }
        __syncthreads();
    }

    // C/D layout: col = lane&15, row = (lane>>4)*4 + reg
    if (left) {
        #pragma unroll
        for (int mi = 0; mi < 2; mi++) {
            #pragma unroll
            for (int ni = 0; ni < 2; ni++) {
                const int row = m0 + wy * 32 + mi * 16 + lk * 4;   // i (=k)
                const int col = n0 + wx * 32 + ni * 16 + lr;       // e
                const float bl = b_lin[col];
                float4 o;
                o.x = acc[mi][ni][0] + bl;
                o.y = acc[mi][ni][1] + bl;
                o.z = acc[mi][ni][2] + bl;
                o.w = acc[mi][ni][3] + bl;
                *(float4*)(LpT + b * 131072 + (row >> 2) * 2048 + col * 4) = o;
            }
        }
    } else {
        unsigned short* R2b = R2 + b * 131072;
        #pragma unroll
        for (int mi = 0; mi < 2; mi++) {
            #pragma unroll
            for (int ni = 0; ni < 2; ni++) {
                const int row = m0 + wy * 32 + mi * 16 + lk * 4;   // e base (4)
                const int col = n0 + wx * 32 + ni * 16 + lr;       // j
                ushort4 o;
                o.x = f2bf(acc[mi][ni][0]);
                o.y = f2bf(acc[mi][ni][1]);
                o.z = f2bf(acc[mi][ni][2]);
                o.w = f2bf(acc[mi][ni][3]);
                *(ushort4*)(R2b + (row >> 3) * 2048 + col * 8 + (row & 7)) = o;
            }
        }
    }
}

// ---------------------------------------------------------------------------
// Kernel 2: score + softmax + MFMA matvec, i-SPLIT for 4 blocks/CU.
// grid 1024 = (it2 = 2-row i-tile, 0..127) x (b = blk&7); 512 thr = 256 j x
// 2 e-halves. 8 waves/block, 4 blocks/CU (2048 thr) -> independent blocks
// overlap each other's serial phases (uL/softmax/matvec/barriers) with score
// VALU work — the 2-blocks/CU lockstep was the ~50% duty ceiling.
// NO cross-block communication (r6/r7: device-scope fences stall the chip).
// L/a stream via wave-uniform global reads (float2 per e now); R bf16 stream
// depth-2 prefetch; matvec x-fragments for kt0..3 prefetched pre-softmax.
// score[i][j] = 0.6*(uL[i]+uR[j]) + 0.4*sum_e a[e]*|L[i,e]+R[e,j]| + bias
// ---------------------------------------------------------------------------
__global__ __launch_bounds__(512, 8) void attn_kernel(
    const unsigned short* __restrict__ xbf,   // (8,256,256) bf16 x[b][w][j]
    const float* __restrict__ LpT,            // (8,64,512,4) fp32, b_lin folded
    const unsigned int* __restrict__ R2u,     // packed bf16 pairs
    const float* __restrict__ a,              // (512)
    const float* __restrict__ bias,           // (256,256)
    float* __restrict__ out)                  // (8,256,256)
{
    const int blk  = (int)blockIdx.x;
    const int b    = blk & 7;
    const int it2  = blk >> 3;                // 0..127 (2-row i tile)
    const int i0   = it2 * 2;
    const int tid  = threadIdx.x;             // 0..511
    const int j    = tid & 255;
    const int wv   = tid >> 6;                // 0..7
    const int lane = tid & 63;

    __shared__ float acc2P[2][2][256];        // 4 KB [e-half][i][j]
    __shared__ float rgp[2][256];             // 2 KB
    __shared__ float u15p[8][2];
    __shared__ unsigned short atbf[16 * 264]; // 8.25 KB (rows 2..15 unused)

    // wave-uniform e-half index (readfirstlane -> SGPR)
    const int eh = __builtin_amdgcn_readfirstlane(tid >> 8);  // 0..1

    // uniform stream bases. LpT blocked layout: [it4][e][4i]; this block's
    // two i-rows sit at sub-offset (it2&1)*2 within the 4-i group.
    const float* Lq = LpT + b * 131072 + (it2 >> 1) * 2048 + (it2 & 1) * 2
                    + eh * 256 * 4;           // value for e: float2 at Lq+e*4
    const float* aq = a + eh * 256;
    const uint4* Rq = (const uint4*)(R2u + b * 65536) + (eh * 32) * 256 + j;

    // ---- R prefetch, depth 2 (named regs)
    uint4 rb0 = Rq[0];
    uint4 rb1 = Rq[256];

    // ---- uL partials: all 8 waves, e = tid (512 e). No barrier before
    // score: u15p is only read after the post-score barrier.
    {
        const float2 lv = *(const float2*)(LpT + b * 131072 + (it2 >> 1) * 2048
                                           + tid * 4 + (it2 & 1) * 2);
        const float ae = a[tid];
        float p0 = ae * lv.x, p1 = ae * lv.y;
        #pragma unroll
        for (int off = 32; off; off >>= 1) {
            p0 += __shfl_xor(p0, off);
            p1 += __shfl_xor(p1, off);
        }
        if (lane == 0) { u15p[wv][0] = p0; u15p[wv][1] = p1; }
    }

    // ---- score: 256 e per thread (e-half), 2 i rows, uniform L/a loads
    float acc0 = 0.f, acc1 = 0.f, rsum = 0.f;

    #pragma unroll 2
    for (int tk = 0; tk < 32; tk++) {
        uint4 rb2;
        if (tk < 30) rb2 = Rq[(tk + 2) * 256];
        float r[8];
        r[0] = bf_lo(rb0.x); r[1] = bf_hi(rb0.x);
        r[2] = bf_lo(rb0.y); r[3] = bf_hi(rb0.y);
        r[4] = bf_lo(rb0.z); r[5] = bf_hi(rb0.z);
        r[6] = bf_lo(rb0.w); r[7] = bf_hi(rb0.w);
        #pragma unroll
        for (int g = 0; g < 2; g++) {
            const float4 av4 = *(const float4*)(aq + tk * 8 + g * 4);
            const float2 l0 = *(const float2*)(Lq + (tk * 8 + g * 4 + 0) * 4);
            const float2 l1 = *(const float2*)(Lq + (tk * 8 + g * 4 + 1) * 4);
            const float2 l2 = *(const float2*)(Lq + (tk * 8 + g * 4 + 2) * 4);
            const float2 l3 = *(const float2*)(Lq + (tk * 8 + g * 4 + 3) * 4);
            const float rv0 = r[g * 4 + 0];
            const float rv1 = r[g * 4 + 1];
            const float rv2 = r[g * 4 + 2];
            const float rv3 = r[g * 4 + 3];
            rsum = fmaf(av4.x, rv0, rsum);
            acc0 = fmaf(av4.x, fabsf(l0.x + rv0), acc0);
            acc1 = fmaf(av4.x, fabsf(l0.y + rv0), acc1);
            rsum = fmaf(av4.y, rv1, rsum);
            acc0 = fmaf(av4.y, fabsf(l1.x + rv1), acc0);
            acc1 = fmaf(av4.y, fabsf(l1.y + rv1), acc1);
            rsum = fmaf(av4.z, rv2, rsum);
            acc0 = fmaf(av4.z, fabsf(l2.x + rv2), acc0);
            acc1 = fmaf(av4.z, fabsf(l2.y + rv2), acc1);
            rsum = fmaf(av4.w, rv3, rsum);
            acc0 = fmaf(av4.w, fabsf(l3.x + rv3), acc0);
            acc1 = fmaf(av4.w, fabsf(l3.y + rv3), acc1);
        }
        rb0 = rb1;
        rb1 = rb2;
    }
    acc2P[eh][0][j] = acc0;
    acc2P[eh][1][j] = acc1;
    rgp[eh][j] = rsum;
    __syncthreads();

    // ---- prefetch matvec x-fragments (kt 0..3, first w-tile) BEFORE the
    // softmax barrier: the 6 non-softmax waves' load latency hides under
    // softmax; 16 VGPR.
    const int lr = lane & 15;
    const int lk = lane >> 4;
    const unsigned short* xw0 = xbf + b * 65536 + (wv * 16 + lr) * 256;
    const bf16x8 px0 = *(const bf16x8*)(xw0 + 0 * 32 + lk * 8);
    const bf16x8 px1 = *(const bf16x8*)(xw0 + 1 * 32 + lk * 8);
    const bf16x8 px2 = *(const bf16x8*)(xw0 + 2 * 32 + lk * 8);
    const bf16x8 px3 = *(const bf16x8*)(xw0 + 3 * 32 + lk * 8);

    // ---- softmax (combine folded in): wave i (wv<2) -> row i
    if (wv < 2) {
        const int i = wv;
        float u15 = 0.f;
        #pragma unroll
        for (int q = 0; q < 8; q++) u15 += u15p[q][i];
        u15 *= 0.6f;
        float v[4];
        float m = -1e30f;
        #pragma unroll
        for (int u = 0; u < 4; u++) {
            const int jj = lane + 64 * u;
            const float uR = rgp[0][jj] + rgp[1][jj];
            const float ab = acc2P[0][i][jj] + acc2P[1][i][jj];
            v[u] = u15 + 0.6f * uR + 0.4f * ab + bias[(i0 + i) * 256 + jj];
            m = fmaxf(m, v[u]);
        }
        #pragma unroll
        for (int off = 32; off; off >>= 1) m = fmaxf(m, __shfl_xor(m, off));
        float ssum = 0.f;
        #pragma unroll
        for (int u = 0; u < 4; u++) { v[u] = __expf(v[u] - m); ssum += v[u]; }
        #pragma unroll
        for (int off = 32; off; off >>= 1) ssum += __shfl_xor(ssum, off);
        const float inv = 1.f / ssum;
        #pragma unroll
        for (int u = 0; u < 4; u++)
            atbf[i * 264 + lane + 64 * u] = f2bf(v[u] * inv);
    }
    __syncthreads();

    // ---- matvec via MFMA: D[i][w] = sum_j attn[i][j] * x[b][w][j]
    // 8 waves x 2 w-tiles. atbf rows 2..15 are garbage LDS but only pollute
    // D rows 2..15, which are never stored (float2 of regs 0..1 at lk==0).
    {
        // w-tile wv (uses prefetched kt 0..3)
        f32x4 hacc = (f32x4){0.f, 0.f, 0.f, 0.f};
        {
            const bf16x8 a0 = *(const bf16x8*)&atbf[lr * 264 + 0 * 32 + lk * 8];
            hacc = __builtin_amdgcn_mfma_f32_16x16x32_bf16(a0, px0, hacc, 0, 0, 0);
            const bf16x8 a1 = *(const bf16x8*)&atbf[lr * 264 + 1 * 32 + lk * 8];
            hacc = __builtin_amdgcn_mfma_f32_16x16x32_bf16(a1, px1, hacc, 0, 0, 0);
            const bf16x8 a2 = *(const bf16x8*)&atbf[lr * 264 + 2 * 32 + lk * 8];
            hacc = __builtin_amdgcn_mfma_f32_16x16x32_bf16(a2, px2, hacc, 0, 0, 0);
            const bf16x8 a3 = *(const bf16x8*)&atbf[lr * 264 + 3 * 32 + lk * 8];
            hacc = __builtin_amdgcn_mfma_f32_16x16x32_bf16(a3, px3, hacc, 0, 0, 0);
            #pragma unroll
            for (int kt = 4; kt < 8; kt++) {
                const bf16x8 av = *(const bf16x8*)&atbf[lr * 264 + kt * 32 + lk * 8];
                const bf16x8 bv = *(const bf16x8*)(xw0 + kt * 32 + lk * 8);
                hacc = __builtin_amdgcn_mfma_f32_16x16x32_bf16(av, bv, hacc, 0, 0, 0);
            }
        }
        if (lk == 0) {
            float2 o;
            o.x = sigmoidf_(hacc[0]);
            o.y = sigmoidf_(hacc[1]);
            *(float2*)(out + b * 65536 + (wv * 16 + lr) * 256 + i0) = o;
        }
        // w-tile wv+8
        const int nt = wv + 8;
        f32x4 hacc2 = (f32x4){0.f, 0.f, 0.f, 0.f};
        const unsigned short* xw = xbf + b * 65536 + (nt * 16 + lr) * 256;
        #pragma unroll
        for (int kt = 0; kt < 8; kt++) {
            const bf16x8 av = *(const bf16x8*)&atbf[lr * 264 + kt * 32 + lk * 8];
            const bf16x8 bv = *(const bf16x8*)(xw + kt * 32 + lk * 8);
            hacc2 = __builtin_amdgcn_mfma_f32_16x16x32_bf16(av, bv, hacc2, 0, 0, 0);
        }
        if (lk == 0) {
            float2 o;
            o.x = sigmoidf_(hacc2[0]);
            o.y = sigmoidf_(hacc2[1]);
            *(float2*)(out + b * 65536 + (nt * 16 + lr) * 256 + i0) = o;
        }
    }
}

extern "C" void kernel_launch(void* const* d_in, const int* in_sizes, int n_in,
                              void* d_out, int out_size, void* d_ws, size_t ws_size,
                              hipStream_t stream) {
    const float* x     = (const float*)d_in[0];
    const float* W     = (const float*)d_in[1];
    const float* b_lin = (const float*)d_in[2];
    const float* a     = (const float*)d_in[3];
    const float* bias  = (const float*)d_in[4];
    float* out = (float*)d_out;

    char* ws = (char*)d_ws;
    float*          LpT = (float*)ws;                          // 4 MB
    unsigned short* R2  = (unsigned short*)(ws + (4 << 20));   // 2 MB
    unsigned short* xbf = (unsigned short*)(ws + (6 << 20));   // 1 MB

    mfma_gemm_kernel<<<dim3(96, 8), 256, 0, stream>>>(x, W, b_lin, LpT, R2, xbf);
    attn_kernel<<<1024, 512, 0, stream>>>(xbf, LpT, (const unsigned int*)R2,
                                          a, bias, out);
}

// Round 9
// 98.558 us; speedup vs baseline: 4.9063x; 1.1139x over previous
//
#include <hip/hip_runtime.h>
#include <math.h>

typedef float f32x4 __attribute__((ext_vector_type(4)));
typedef __bf16 bf16x8 __attribute__((ext_vector_type(8)));
typedef unsigned short u16x8 __attribute__((ext_vector_type(8)));

__device__ __forceinline__ unsigned short f2bf(float f) {
    union { float f; unsigned int u; } v; v.f = f;
    unsigned int u = v.u;
    return (unsigned short)((u + 0x7fffu + ((u >> 16) & 1u)) >> 16);  // RNE
}
__device__ __forceinline__ float bf_lo(unsigned int d) {
    union { unsigned int u; float f; } v; v.u = d << 16; return v.f;
}
__device__ __forceinline__ float bf_hi(unsigned int d) {
    union { unsigned int u; float f; } v; v.u = d & 0xffff0000u; return v.f;
}
__device__ __forceinline__ float sigmoidf_(float v) {
    return 1.f / (1.f + __expf(-v));
}

// ---------------------------------------------------------------------------
// Kernel 1 (exact r1-bench version, proven 101.2): fused convert + MFMA bf16
// GEMM + x->bf16 conversion.
//  left  (t<32):  -> LpT[b][i>>2][e][i&3] = C + b_lin[e]   (fp32 transposed)
//  right (32<=t<64): -> R2[b][(e>>3)*2048 + j*8 + (e&7)] = bf16(C)
//  conv  (t>=64): xbf = bf16(x)
// ---------------------------------------------------------------------------
__global__ __launch_bounds__(256) void mfma_gemm_kernel(
    const float* __restrict__ x,      // (8,256,256) x[b][w][k]
    const float* __restrict__ W,      // (512,512)
    const float* __restrict__ b_lin,  // (512)
    float* __restrict__ LpT,          // (8,64,512,4) fp32  L^T blocked
    unsigned short* __restrict__ R2,  // (8, 512e x 256j packed)
    unsigned short* __restrict__ xbf) // (8,256,256) bf16
{
    const int b = blockIdx.y;
    const int t = blockIdx.x;

    if (t >= 64) {   // ---- x -> bf16 straight conversion
        const int idx = b * 65536 + (t - 64) * 2048 + threadIdx.x * 8;
        const float4 v0 = *(const float4*)(x + idx);
        const float4 v1 = *(const float4*)(x + idx + 4);
        u16x8 o;
        o[0] = f2bf(v0.x); o[1] = f2bf(v0.y); o[2] = f2bf(v0.z); o[3] = f2bf(v0.w);
        o[4] = f2bf(v1.x); o[5] = f2bf(v1.y); o[6] = f2bf(v1.z); o[7] = f2bf(v1.w);
        *(u16x8*)(xbf + idx) = o;
        return;
    }

    const bool left = (t < 32);
    int m0, n0;
    if (left) { m0 = (t >> 3) * 64; n0 = (t & 7) * 64; }
    else      { const int tt = t - 32; m0 = (tt >> 2) * 64; n0 = (tt & 3) * 64; }

    __shared__ unsigned short As[64][72];
    __shared__ unsigned short Bs[64][72];

    unsigned short (*Ts)[72] = left ? As : Bs;   // x^T tile
    unsigned short (*Ds)[72] = left ? Bs : As;   // W tile
    const int cbase = left ? m0 : n0;            // x column base (k or j)
    const int rbase = left ? n0 : m0;            // W row base (e)
    const int coff  = left ? 0 : 256;            // W column offset

    const int tid  = threadIdx.x;
    const int wv   = tid >> 6;
    const int lane = tid & 63;
    const int wy = wv >> 1, wx = wv & 1;
    const int lr = lane & 15;
    const int lk = lane >> 4;

    const float* xb = x + b * 65536;

    f32x4 acc[2][2];
    #pragma unroll
    for (int i = 0; i < 2; i++)
        #pragma unroll
        for (int jj = 0; jj < 2; jj++) acc[i][jj] = (f32x4){0.f, 0.f, 0.f, 0.f};

    const int wl = tid >> 4;         // 0..15
    const int kg = tid & 15;         // 0..15
    const int dr = tid >> 2;         // 0..63
    const int dc = (tid & 3) * 16;

    for (int k0 = 0; k0 < 256; k0 += 64) {
        #pragma unroll
        for (int p = 0; p < 4; p++) {
            const int w = wl + 16 * p;
            const float4 v = *(const float4*)(xb + (k0 + w) * 256 + cbase + kg * 4);
            Ts[kg * 4 + 0][w] = f2bf(v.x);
            Ts[kg * 4 + 1][w] = f2bf(v.y);
            Ts[kg * 4 + 2][w] = f2bf(v.z);
            Ts[kg * 4 + 3][w] = f2bf(v.w);
        }
        {
            const float* src = W + (rbase + dr) * 512 + coff + k0 + dc;
            const float4 v0 = *(const float4*)(src);
            const float4 v1 = *(const float4*)(src + 4);
            const float4 v2 = *(const float4*)(src + 8);
            const float4 v3 = *(const float4*)(src + 12);
            u16x8 o0, o1;
            o0[0]=f2bf(v0.x); o0[1]=f2bf(v0.y); o0[2]=f2bf(v0.z); o0[3]=f2bf(v0.w);
            o0[4]=f2bf(v1.x); o0[5]=f2bf(v1.y); o0[6]=f2bf(v1.z); o0[7]=f2bf(v1.w);
            o1[0]=f2bf(v2.x); o1[1]=f2bf(v2.y); o1[2]=f2bf(v2.z); o1[3]=f2bf(v2.w);
            o1[4]=f2bf(v3.x); o1[5]=f2bf(v3.y); o1[6]=f2bf(v3.z); o1[7]=f2bf(v3.w);
            *(u16x8*)&Ds[dr][dc]     = o0;
            *(u16x8*)&Ds[dr][dc + 8] = o1;
        }
        __syncthreads();
        #pragma unroll
        for (int kk = 0; kk < 64; kk += 32) {
            const bf16x8 a0 = *(const bf16x8*)&As[wy * 32 + lr][kk + lk * 8];
            const bf16x8 a1 = *(const bf16x8*)&As[wy * 32 + 16 + lr][kk + lk * 8];
            const bf16x8 b0 = *(const bf16x8*)&Bs[wx * 32 + lr][kk + lk * 8];
            const bf16x8 b1 = *(const bf16x8*)&Bs[wx * 32 + 16 + lr][kk + lk * 8];
            acc[0][0] = __builtin_amdgcn_mfma_f32_16x16x32_bf16(a0, b0, acc[0][0], 0, 0, 0);
            acc[0][1] = __builtin_amdgcn_mfma_f32_16x16x32_bf16(a0, b1, acc[0][1], 0, 0, 0);
            acc[1][0] = __builtin_amdgcn_mfma_f32_16x16x32_bf16(a1, b0, acc[1][0], 0, 0, 0);
            acc[1][1] = __builtin_amdgcn_mfma_f32_16x16x32_bf16(a1, b1, acc[1][1], 0, 0, 0);
        }
        __syncthreads();
    }

    // C/D layout: col = lane&15, row = (lane>>4)*4 + reg
    if (left) {
        #pragma unroll
        for (int mi = 0; mi < 2; mi++) {
            #pragma unroll
            for (int ni = 0; ni < 2; ni++) {
                const int row = m0 + wy * 32 + mi * 16 + lk * 4;   // i (=k)
                const int col = n0 + wx * 32 + ni * 16 + lr;       // e
                const float bl = b_lin[col];
                float4 o;
                o.x = acc[mi][ni][0] + bl;
                o.y = acc[mi][ni][1] + bl;
                o.z = acc[mi][ni][2] + bl;
                o.w = acc[mi][ni][3] + bl;
                *(float4*)(LpT + b * 131072 + (row >> 2) * 2048 + col * 4) = o;
            }
        }
    } else {
        unsigned short* R2b = R2 + b * 131072;
        #pragma unroll
        for (int mi = 0; mi < 2; mi++) {
            #pragma unroll
            for (int ni = 0; ni < 2; ni++) {
                const int row = m0 + wy * 32 + mi * 16 + lk * 4;   // e base (4)
                const int col = n0 + wx * 32 + ni * 16 + lr;       // j
                ushort4 o;
                o.x = f2bf(acc[mi][ni][0]);
                o.y = f2bf(acc[mi][ni][1]);
                o.z = f2bf(acc[mi][ni][2]);
                o.w = f2bf(acc[mi][ni][3]);
                *(ushort4*)(R2b + (row >> 3) * 2048 + col * 8 + (row & 7)) = o;
            }
        }
    }
}

// ---------------------------------------------------------------------------
// Kernel 2 (r1 structure, proven ~35us, + two pure load-hoists):
// grid 512 = (i-tile of 4) x (b = blk&7); 1024 thr = 256 j x 4 e-quarters.
// L/a stream via wave-uniform global reads (SGPR-promoted); R bf16 stream,
// depth-2 prefetch; 2 block barriers.
// NEW vs r1 (scheduling only, same addresses, no semantic change):
//  (a) matvec x-fragments kt0..3 loaded BEFORE the post-score barrier
//  (b) softmax bias values loaded BEFORE the post-score barrier
// Both hide L2 latency under barrier-drain + softmax instead of after it.
// score[i][j] = 0.6*(uL[i]+uR[j]) + 0.4*sum_e a[e]*|L[i,e]+R[e,j]| + bias
// ---------------------------------------------------------------------------
__global__ __launch_bounds__(1024, 8) void attn_kernel(
    const unsigned short* __restrict__ xbf,   // (8,256,256) bf16 x[b][w][j]
    const float* __restrict__ LpT,            // (8,64,512,4) fp32, b_lin folded
    const unsigned int* __restrict__ R2u,     // packed bf16 pairs
    const float* __restrict__ a,              // (512)
    const float* __restrict__ bias,           // (256,256)
    float* __restrict__ out)                  // (8,256,256)
{
    const int b     = blockIdx.x & 7;
    const int itile = blockIdx.x >> 3;        // 0..63
    const int i0    = itile * 4;
    const int tid   = threadIdx.x;
    const int j     = tid & 255;
    const int wv    = tid >> 6;               // 0..15
    const int lane  = tid & 63;

    __shared__ float acc2P[4][4][256];        // 16 KB  [e-quarter][i][j]
    __shared__ float rgp[4][256];             // 4 KB   [e-quarter][j]
    __shared__ float u15p[8][4];
    __shared__ unsigned short atbf[16 * 264]; // 8.25 KB (rows 4..15 unused)

    // wave-uniform e-quarter index (readfirstlane -> SGPR -> scalar loads)
    const int ehq = __builtin_amdgcn_readfirstlane(tid >> 8);  // 0..3

    // uniform stream bases
    const float* Lq = LpT + b * 131072 + itile * 2048 + ehq * 512;  // [e_loc][4]
    const float* aq = a + ehq * 128;
    const uint4* Rq = (const uint4*)(R2u + b * 65536) + (ehq * 16) * 256 + j;

    // ---- R prefetch, depth 2 (named regs, no dynamic indexing)
    uint4 rb0 = Rq[0];
    uint4 rb1 = Rq[256];

    // ---- uL partials: waves 0..7; waves 8..15 go straight to score
    if (tid < 512) {
        const float4 lv = *(const float4*)(LpT + b * 131072 + itile * 2048 + tid * 4);
        const float ae = a[tid];
        float p0 = ae * lv.x, p1 = ae * lv.y, p2 = ae * lv.z, p3 = ae * lv.w;
        #pragma unroll
        for (int off = 32; off; off >>= 1) {
            p0 += __shfl_xor(p0, off);
            p1 += __shfl_xor(p1, off);
            p2 += __shfl_xor(p2, off);
            p3 += __shfl_xor(p3, off);
        }
        if (lane == 0) {
            u15p[wv][0] = p0; u15p[wv][1] = p1;
            u15p[wv][2] = p2; u15p[wv][3] = p3;
        }
    }

    // ---- score: 128 e per thread (e-quarter), 4 i rows, uniform L/a loads
    float acc0 = 0.f, acc1 = 0.f, acc2 = 0.f, acc3 = 0.f, rsum = 0.f;

    #pragma unroll 2
    for (int tk = 0; tk < 16; tk++) {
        uint4 rb2;
        if (tk < 14) rb2 = Rq[(tk + 2) * 256];
        float r[8];
        r[0] = bf_lo(rb0.x); r[1] = bf_hi(rb0.x);
        r[2] = bf_lo(rb0.y); r[3] = bf_hi(rb0.y);
        r[4] = bf_lo(rb0.z); r[5] = bf_hi(rb0.z);
        r[6] = bf_lo(rb0.w); r[7] = bf_hi(rb0.w);
        #pragma unroll
        for (int g = 0; g < 2; g++) {
            const float4 av4 = *(const float4*)(aq + tk * 8 + g * 4);
            const float4 l0 = *(const float4*)(Lq + (tk * 8 + g * 4 + 0) * 4);
            const float4 l1 = *(const float4*)(Lq + (tk * 8 + g * 4 + 1) * 4);
            const float4 l2 = *(const float4*)(Lq + (tk * 8 + g * 4 + 2) * 4);
            const float4 l3 = *(const float4*)(Lq + (tk * 8 + g * 4 + 3) * 4);
            const float rv0 = r[g * 4 + 0];
            const float rv1 = r[g * 4 + 1];
            const float rv2 = r[g * 4 + 2];
            const float rv3 = r[g * 4 + 3];
            rsum = fmaf(av4.x, rv0, rsum);
            acc0 = fmaf(av4.x, fabsf(l0.x + rv0), acc0);
            acc1 = fmaf(av4.x, fabsf(l0.y + rv0), acc1);
            acc2 = fmaf(av4.x, fabsf(l0.z + rv0), acc2);
            acc3 = fmaf(av4.x, fabsf(l0.w + rv0), acc3);
            rsum = fmaf(av4.y, rv1, rsum);
            acc0 = fmaf(av4.y, fabsf(l1.x + rv1), acc0);
            acc1 = fmaf(av4.y, fabsf(l1.y + rv1), acc1);
            acc2 = fmaf(av4.y, fabsf(l1.z + rv1), acc2);
            acc3 = fmaf(av4.y, fabsf(l1.w + rv1), acc3);
            rsum = fmaf(av4.z, rv2, rsum);
            acc0 = fmaf(av4.z, fabsf(l2.x + rv2), acc0);
            acc1 = fmaf(av4.z, fabsf(l2.y + rv2), acc1);
            acc2 = fmaf(av4.z, fabsf(l2.z + rv2), acc2);
            acc3 = fmaf(av4.z, fabsf(l2.w + rv2), acc3);
            rsum = fmaf(av4.w, rv3, rsum);
            acc0 = fmaf(av4.w, fabsf(l3.x + rv3), acc0);
            acc1 = fmaf(av4.w, fabsf(l3.y + rv3), acc1);
            acc2 = fmaf(av4.w, fabsf(l3.z + rv3), acc2);
            acc3 = fmaf(av4.w, fabsf(l3.w + rv3), acc3);
        }
        rb0 = rb1;
        rb1 = rb2;
    }
    acc2P[ehq][0][j] = acc0;
    acc2P[ehq][1][j] = acc1;
    acc2P[ehq][2][j] = acc2;
    acc2P[ehq][3][j] = acc3;
    rgp[ehq][j] = rsum;

    // ---- (a) hoist matvec x-fragment loads (kt 0..3) above the barrier:
    // latency hides under barrier drain + softmax. Same addresses as before.
    const int lr = lane & 15;
    const int lk = lane >> 4;
    const unsigned short* xw = xbf + b * 65536 + (wv * 16 + lr) * 256;
    const bf16x8 px0 = *(const bf16x8*)(xw + 0 * 32 + lk * 8);
    const bf16x8 px1 = *(const bf16x8*)(xw + 1 * 32 + lk * 8);
    const bf16x8 px2 = *(const bf16x8*)(xw + 2 * 32 + lk * 8);
    const bf16x8 px3 = *(const bf16x8*)(xw + 3 * 32 + lk * 8);

    // ---- (b) hoist softmax bias loads above the barrier
    float bs0 = 0.f, bs1 = 0.f, bs2 = 0.f, bs3 = 0.f;
    if (wv < 4) {
        const float* brow = bias + (i0 + wv) * 256 + lane;
        bs0 = brow[0];
        bs1 = brow[64];
        bs2 = brow[128];
        bs3 = brow[192];
    }
    __syncthreads();

    // ---- softmax (combine folded in): wave i (wv<4) -> row i
    if (wv < 4) {
        const int i = wv;
        float u15 = 0.f;
        #pragma unroll
        for (int q = 0; q < 8; q++) u15 += u15p[q][i];   // LDS broadcast reads
        u15 *= 0.6f;
        float v[4];
        const float bsv[4] = { bs0, bs1, bs2, bs3 };
        float m = -1e30f;
        #pragma unroll
        for (int u = 0; u < 4; u++) {
            const int jj = lane + 64 * u;
            const float uR = rgp[0][jj] + rgp[1][jj] + rgp[2][jj] + rgp[3][jj];
            const float ab = acc2P[0][i][jj] + acc2P[1][i][jj]
                           + acc2P[2][i][jj] + acc2P[3][i][jj];
            v[u] = u15 + 0.6f * uR + 0.4f * ab + bsv[u];
            m = fmaxf(m, v[u]);
        }
        #pragma unroll
        for (int off = 32; off; off >>= 1) m = fmaxf(m, __shfl_xor(m, off));
        float ssum = 0.f;
        #pragma unroll
        for (int u = 0; u < 4; u++) { v[u] = __expf(v[u] - m); ssum += v[u]; }
        #pragma unroll
        for (int off = 32; off; off >>= 1) ssum += __shfl_xor(ssum, off);
        const float inv = 1.f / ssum;
        #pragma unroll
        for (int u = 0; u < 4; u++)
            atbf[i * 264 + lane + 64 * u] = f2bf(v[u] * inv);
    }
    __syncthreads();

    // ---- matvec via MFMA: D[i][w] = sum_j attn[i][j] * x[b][w][j]
    // 16 waves; wave wv handles w-tile wv. atbf rows 4..15 are garbage LDS
    // but only pollute D rows 4..15, which are never stored (lk==0 only).
    // kt 0..3 use the pre-barrier-loaded px fragments.
    {
        f32x4 hacc = (f32x4){0.f, 0.f, 0.f, 0.f};
        const bf16x8 a0 = *(const bf16x8*)&atbf[lr * 264 + 0 * 32 + lk * 8];
        hacc = __builtin_amdgcn_mfma_f32_16x16x32_bf16(a0, px0, hacc, 0, 0, 0);
        const bf16x8 a1 = *(const bf16x8*)&atbf[lr * 264 + 1 * 32 + lk * 8];
        hacc = __builtin_amdgcn_mfma_f32_16x16x32_bf16(a1, px1, hacc, 0, 0, 0);
        const bf16x8 a2 = *(const bf16x8*)&atbf[lr * 264 + 2 * 32 + lk * 8];
        hacc = __builtin_amdgcn_mfma_f32_16x16x32_bf16(a2, px2, hacc, 0, 0, 0);
        const bf16x8 a3 = *(const bf16x8*)&atbf[lr * 264 + 3 * 32 + lk * 8];
        hacc = __builtin_amdgcn_mfma_f32_16x16x32_bf16(a3, px3, hacc, 0, 0, 0);
        #pragma unroll
        for (int kt = 4; kt < 8; kt++) {
            const bf16x8 av = *(const bf16x8*)&atbf[lr * 264 + kt * 32 + lk * 8];
            const bf16x8 bv = *(const bf16x8*)(xw + kt * 32 + lk * 8);
            hacc = __builtin_amdgcn_mfma_f32_16x16x32_bf16(av, bv, hacc, 0, 0, 0);
        }
        if (lk == 0) {
            float4 o;
            o.x = sigmoidf_(hacc[0]);
            o.y = sigmoidf_(hacc[1]);
            o.z = sigmoidf_(hacc[2]);
            o.w = sigmoidf_(hacc[3]);
            *(float4*)(out + b * 65536 + (wv * 16 + lr) * 256 + i0) = o;
        }
    }
}

extern "C" void kernel_launch(void* const* d_in, const int* in_sizes, int n_in,
                              void* d_out, int out_size, void* d_ws, size_t ws_size,
                              hipStream_t stream) {
    const float* x     = (const float*)d_in[0];
    const float* W     = (const float*)d_in[1];
    const float* b_lin = (const float*)d_in[2];
    const float* a     = (const float*)d_in[3];
    const float* bias  = (const float*)d_in[4];
    float* out = (float*)d_out;

    char* ws = (char*)d_ws;
    float*          LpT = (float*)ws;                          // 4 MB
    unsigned short* R2  = (unsigned short*)(ws + (4 << 20));   // 2 MB
    unsigned short* xbf = (unsigned short*)(ws + (6 << 20));   // 1 MB

    mfma_gemm_kernel<<<dim3(96, 8), 256, 0, stream>>>(x, W, b_lin, LpT, R2, xbf);
    attn_kernel<<<512, 1024, 0, stream>>>(xbf, LpT, (const unsigned int*)R2,
                                          a, bias, out);
}